// Round 3
// baseline (217.778 us; speedup 1.0000x reference)
//
#include <hip/hip_runtime.h>
#include <hip/hip_bf16.h>
#include <stdint.h>

// ---------------- constants ----------------
constexpr int Nn = 8192;
constexpr int Dd = 1024;
constexpr float kAlpha = 0.1f;
constexpr float kEps = 1e-7f;
constexpr float kInf = 3.0e38f;

constexpr int BM = 128, BN = 128, BK = 32;
constexpr int NB = Nn / BM;               // 64 row/col blocks
constexpr int NPAIR = NB * (NB + 1) / 2;  // 2080 upper-triangle tile pairs

using bfx8 = __attribute__((ext_vector_type(8))) __bf16;   // MFMA A/B frag (4 VGPRs)
using f32x4 = __attribute__((ext_vector_type(4))) float;   // MFMA C/D frag

__device__ __forceinline__ unsigned short f2bf(float f) {
  union { float f; unsigned int u; } v; v.f = f;
  unsigned int u = v.u;
  u = u + 0x7fffu + ((u >> 16) & 1u);  // RNE
  return (unsigned short)(u >> 16);
}

__device__ __forceinline__ void min2_insert(float& m1, float& m2, float x) {
  const float lo = fminf(m1, x);
  const float hi = fmaxf(m1, x);
  m1 = lo;
  m2 = fminf(m2, hi);
}

__device__ __forceinline__ void min2_merge(float& m1, float& m2, float o1, float o2) {
  m2 = fminf(fminf(m2, o2), fmaxf(m1, o1));
  m1 = fminf(m1, o1);
}

// ---------------- prep: fp32 -> bf16 + row sq-norms ----------------
__global__ __launch_bounds__(256) void prep_kernel(const float* __restrict__ H,
                                                   unsigned short* __restrict__ Hb,
                                                   float* __restrict__ xn) {
  const int wave = threadIdx.x >> 6;
  const int lane = threadIdx.x & 63;
  const int row = blockIdx.x * 4 + wave;
  const float4* src = (const float4*)(H + (size_t)row * Dd);
  ushort4* dst = (ushort4*)(Hb + (size_t)row * Dd);
  float acc = 0.f;
#pragma unroll
  for (int i = 0; i < 4; ++i) {
    float4 v = src[lane + 64 * i];
    acc = fmaf(v.x, v.x, acc);
    acc = fmaf(v.y, v.y, acc);
    acc = fmaf(v.z, v.z, acc);
    acc = fmaf(v.w, v.w, acc);
    ushort4 o;
    o.x = f2bf(v.x); o.y = f2bf(v.y); o.z = f2bf(v.z); o.w = f2bf(v.w);
    dst[lane + 64 * i] = o;
  }
#pragma unroll
  for (int off = 32; off; off >>= 1) acc += __shfl_xor(acc, off, 64);
  if (lane == 0) xn[row] = acc;
}

// ---------------- main: symmetric fused GEMM + triplet reductions ----------------
// grid = 2080 upper-triangle pairs (I<=J). One 128x128 Gram tile per block,
// reduced BOTH ways (row side -> P[I][J], transposed side -> P[J][I]).
// K-loop: double-buffered LDS, one barrier per iter, prefetch overlaps compute
// (stage(next); compute(cur); barrier) — m99-style pipeline.
__global__ __launch_bounds__(256, 4) void triplet_main(
    const unsigned short* __restrict__ Hb, const float* __restrict__ xn,
    const int* __restrict__ lab, float* __restrict__ wsMax,
    float* __restrict__ wsM1, float* __restrict__ wsM2) {
  __shared__ __align__(16) unsigned char smem[32768];  // 2 x (As 8K + Bs 8K)

  const int tid = threadIdx.x;
  const int wave = tid >> 6;
  const int lane = tid & 63;
  const int quad = lane >> 4;
  const int l15 = lane & 15;
  const int wm = wave & 1;
  const int wn = wave >> 1;

  // decode pair index -> (I, J), I <= J
  int b = blockIdx.x, I = 0;
  while (b >= NB - I) { b -= NB - I; ++I; }
  const int J = I + b;
  const bool diag = (I == J);

  const int rowBase = I * BM;
  const int colBase = J * BN;

  // per-lane metadata hoisted above the K-loop (hides the latency)
  int lr[16]; float xr[16];
#pragma unroll
  for (int m = 0; m < 4; ++m)
#pragma unroll
    for (int r = 0; r < 4; ++r) {
      const int row = rowBase + wm * 64 + m * 16 + quad * 4 + r;
      lr[m * 4 + r] = lab[row];
      xr[m * 4 + r] = xn[row];
    }
  int lc[4]; float xc[4];
#pragma unroll
  for (int n = 0; n < 4; ++n) {
    const int col = colBase + wn * 64 + n * 16 + l15;
    lc[n] = lab[col];
    xc[n] = xn[col];
  }

  // staging map: wave stages rows [wave*32 + j*16, +16); lane -> (row, 16B seg)
  const int stRow = wave * 32 + (lane >> 2);
  const int stCol = (lane & 3) * 8;  // short offset within a 32-short row
  const unsigned short* gA = Hb + (size_t)(rowBase + stRow) * Dd + stCol;
  const unsigned short* gB = Hb + (size_t)(colBase + stRow) * Dd + stCol;

  auto stage = [&](int buf, int kt) {
    unsigned short* s = (unsigned short*)(smem + (buf << 14));
#pragma unroll
    for (int j = 0; j < 2; ++j) {
      __builtin_amdgcn_global_load_lds(
          (const __attribute__((address_space(1))) void*)(gA + j * 16 * Dd + kt),
          (__attribute__((address_space(3))) void*)&s[(wave * 2 + j) * 512],
          16, 0, 0);
      __builtin_amdgcn_global_load_lds(
          (const __attribute__((address_space(1))) void*)(gB + j * 16 * Dd + kt),
          (__attribute__((address_space(3))) void*)&s[4096 + (wave * 2 + j) * 512],
          16, 0, 0);
    }
  };

  f32x4 acc[4][4];
#pragma unroll
  for (int m = 0; m < 4; ++m)
#pragma unroll
    for (int n = 0; n < 4; ++n) acc[m][n] = {0.f, 0.f, 0.f, 0.f};

  stage(0, 0);
  __syncthreads();  // buf0 ready (vmcnt drained once, cold)

  constexpr int KIT = Dd / BK;  // 32
  for (int it = 0; it < KIT; ++it) {
    const int cur = it & 1;
    if (it + 1 < KIT) stage(cur ^ 1, (it + 1) * BK);  // prefetch flies under compute

    const unsigned short* s = (const unsigned short*)(smem + (cur << 14));
    bfx8 a[4], bb[4];
#pragma unroll
    for (int m = 0; m < 4; ++m)
      a[m] = *(const bfx8*)&s[(wm * 64 + m * 16 + l15) * BK + quad * 8];
#pragma unroll
    for (int n = 0; n < 4; ++n)
      bb[n] = *(const bfx8*)&s[4096 + (wn * 64 + n * 16 + l15) * BK + quad * 8];
#pragma unroll
    for (int m = 0; m < 4; ++m)
#pragma unroll
      for (int n = 0; n < 4; ++n)
        acc[m][n] = __builtin_amdgcn_mfma_f32_16x16x32_bf16(a[m], bb[n], acc[m][n], 0, 0, 0);

    __syncthreads();  // drains prefetch (had full compute to fly); frees cur for reuse
  }

  // ---- epilogue: dist = xr + xc - 2*G; both-sided masked reductions ----
  float maxp[16], mn1[16], mn2[16];
#pragma unroll
  for (int s = 0; s < 16; ++s) { maxp[s] = 0.f; mn1[s] = kInf; mn2[s] = kInf; }
  float tmaxp[4], tmn1[4], tmn2[4];
#pragma unroll
  for (int n = 0; n < 4; ++n) { tmaxp[n] = 0.f; tmn1[n] = kInf; tmn2[n] = kInf; }

  if (!diag) {
#pragma unroll
    for (int m = 0; m < 4; ++m)
#pragma unroll
      for (int n = 0; n < 4; ++n)
#pragma unroll
        for (int r = 0; r < 4; ++r) {
          const int s = m * 4 + r;
          const float d = fmaf(-2.f, acc[m][n][r], xr[s] + xc[n]);
          const bool eq = (lr[s] == lc[n]);
          const float pos = eq ? d : 0.f;
          const float dn = eq ? kInf : d;
          maxp[s] = fmaxf(maxp[s], pos);
          min2_insert(mn1[s], mn2[s], dn);
          tmaxp[n] = fmaxf(tmaxp[n], pos);
          min2_insert(tmn1[n], tmn2[n], dn);
        }
  } else {
#pragma unroll
    for (int m = 0; m < 4; ++m)
#pragma unroll
      for (int n = 0; n < 4; ++n)
#pragma unroll
        for (int r = 0; r < 4; ++r) {
          const int s = m * 4 + r;
          const bool selfp = (wm == wn) && (m == n) && (quad * 4 + r == l15);
          const float d = fmaf(-2.f, acc[m][n][r], xr[s] + xc[n]);
          const bool eq = (lr[s] == lc[n]);
          const float pos = (eq && !selfp) ? d : 0.f;
          const float dn = eq ? kInf : d;  // self is eq -> excluded from negatives
          maxp[s] = fmaxf(maxp[s], pos);
          min2_insert(mn1[s], mn2[s], dn);
        }
  }

  // cross-lane row merge over the 16 column-lanes
#pragma unroll
  for (int off = 1; off < 16; off <<= 1) {
#pragma unroll
    for (int s = 0; s < 16; ++s) {
      const float om = __shfl_xor(maxp[s], off, 64);
      const float o1 = __shfl_xor(mn1[s], off, 64);
      const float o2 = __shfl_xor(mn2[s], off, 64);
      maxp[s] = fmaxf(maxp[s], om);
      min2_merge(mn1[s], mn2[s], o1, o2);
    }
  }

  // ---- LDS scratch phase (reuse buf0 region; K-loop ended with a barrier) ----
  float* rbuf = (float*)smem;        // [2(wm)][64(local)][3]   = 384 floats
  float* tbm = ((float*)smem) + 384; // [2(wm)][2(wn)][4(q)][4(n)][16(l15)] = 1024 each
  float* tb1 = tbm + 1024;
  float* tb2 = tb1 + 1024;

  if (wn == 1 && l15 == 0) {
#pragma unroll
    for (int m = 0; m < 4; ++m)
#pragma unroll
      for (int r = 0; r < 4; ++r) {
        const int s = m * 4 + r;
        const int local = m * 16 + quad * 4 + r;
        rbuf[(wm * 64 + local) * 3 + 0] = maxp[s];
        rbuf[(wm * 64 + local) * 3 + 1] = mn1[s];
        rbuf[(wm * 64 + local) * 3 + 2] = mn2[s];
      }
  }
#pragma unroll
  for (int n = 0; n < 4; ++n) {
    const int idx = (((wm * 2 + wn) * 4 + quad) * 4 + n) * 16 + l15;
    tbm[idx] = tmaxp[n];
    tb1[idx] = tmn1[n];
    tb2[idx] = tmn2[n];
  }
  __syncthreads();

  // row side: wn==0 waves merge rbuf and write P[I][J]
  if (wn == 0 && l15 == 0) {
#pragma unroll
    for (int m = 0; m < 4; ++m)
#pragma unroll
      for (int r = 0; r < 4; ++r) {
        const int s = m * 4 + r;
        const int local = m * 16 + quad * 4 + r;
        float om = rbuf[(wm * 64 + local) * 3 + 0];
        float o1 = rbuf[(wm * 64 + local) * 3 + 1];
        float o2 = rbuf[(wm * 64 + local) * 3 + 2];
        const float M = fmaxf(maxp[s], om);
        float a1 = mn1[s], a2 = mn2[s];
        min2_merge(a1, a2, o1, o2);
        const size_t p = ((size_t)(I * NB + J)) * 128 + wm * 64 + local;
        wsMax[p] = M;
        wsM1[p] = a1;
        wsM2[p] = a2;
      }
  }
  // transposed side: wm==0 waves merge tbuf over {wm2, quad} and write P[J][I]
  if (wm == 0 && !diag) {
    const int tn = lane >> 4;
    const int tl = lane & 15;
    float M = 0.f, a1 = kInf, a2 = kInf;
#pragma unroll
    for (int wm2 = 0; wm2 < 2; ++wm2)
#pragma unroll
      for (int q = 0; q < 4; ++q) {
        const int idx = (((wm2 * 2 + wn) * 4 + q) * 4 + tn) * 16 + tl;
        M = fmaxf(M, tbm[idx]);
        min2_merge(a1, a2, tb1[idx], tb2[idx]);
      }
    const size_t p = ((size_t)(J * NB + I)) * 128 + wn * 64 + lane;
    wsMax[p] = M;
    wsM1[p] = a1;
    wsM2[p] = a2;
  }
}

// ---------------- merge: per-row over 64 col-block partials -> block sums ----
// grid = 256 blocks x 256 threads; block handles 32 rows, 8 threads per row.
__global__ __launch_bounds__(256) void merge_kernel(
    const float* __restrict__ wsMax, const float* __restrict__ wsM1,
    const float* __restrict__ wsM2, float* __restrict__ bsum,
    float* __restrict__ bcnt) {
  const int rl = threadIdx.x & 31;  // row within block
  const int p = threadIdx.x >> 5;   // part 0..7 -> bj in [p*8, p*8+8)
  const int row = blockIdx.x * 32 + rl;
  const int bi = row >> 7;
  const int rr = row & 127;
  float mp = 0.f, m1 = kInf, m2 = kInf;
#pragma unroll
  for (int k = 0; k < 8; ++k) {
    const int bj = p * 8 + k;
    const size_t idx = ((size_t)(bi * NB + bj)) * 128 + rr;
    mp = fmaxf(mp, wsMax[idx]);
    min2_merge(m1, m2, wsM1[idx], wsM2[idx]);
  }
  __shared__ float sm[8][32], s1[8][32], s2[8][32];
  sm[p][rl] = mp; s1[p][rl] = m1; s2[p][rl] = m2;
  __syncthreads();
  float ls = 0.f, lc = 0.f;
  if (threadIdx.x < 32) {
    mp = sm[0][rl]; m1 = s1[0][rl]; m2 = s2[0][rl];
#pragma unroll
    for (int q = 1; q < 8; ++q) {
      mp = fmaxf(mp, sm[q][rl]);
      min2_merge(m1, m2, s1[q][rl], s2[q][rl]);
    }
    const float loss = fmaxf(mp - m2 + kAlpha, 0.f);
    ls = (loss > kEps) ? loss : 0.f;
    lc = (loss > kEps) ? 1.f : 0.f;
  }
  if (threadIdx.x < 64) {
#pragma unroll
    for (int off = 32; off; off >>= 1) {
      ls += __shfl_down(ls, off, 64);
      lc += __shfl_down(lc, off, 64);
    }
    if (threadIdx.x == 0) { bsum[blockIdx.x] = ls; bcnt[blockIdx.x] = lc; }
  }
}

// ---------------- final: reduce 256 block sums, divide ----------------
__global__ __launch_bounds__(256) void final_kernel(const float* __restrict__ bsum,
                                                    const float* __restrict__ bcnt,
                                                    float* __restrict__ out) {
  float s = bsum[threadIdx.x];
  float c = bcnt[threadIdx.x];
#pragma unroll
  for (int off = 32; off; off >>= 1) {
    s += __shfl_down(s, off, 64);
    c += __shfl_down(c, off, 64);
  }
  __shared__ float ss[4], sc[4];
  const int w = threadIdx.x >> 6;
  if ((threadIdx.x & 63) == 0) { ss[w] = s; sc[w] = c; }
  __syncthreads();
  if (threadIdx.x == 0)
    out[0] = (ss[0] + ss[1] + ss[2] + ss[3]) / (sc[0] + sc[1] + sc[2] + sc[3]);
}

// ---------------- launch ----------------
extern "C" void kernel_launch(void* const* d_in, const int* in_sizes, int n_in,
                              void* d_out, int out_size, void* d_ws, size_t ws_size,
                              hipStream_t stream) {
  (void)in_sizes; (void)n_in; (void)out_size; (void)ws_size;
  const float* H = (const float*)d_in[0];
  const int* lab = (const int*)d_in[1];
  float* out = (float*)d_out;

  char* ws = (char*)d_ws;
  unsigned short* Hb = (unsigned short*)ws;                              // 16 MB
  float* xn = (float*)(ws + (size_t)Nn * Dd * sizeof(unsigned short));   // 32 KB
  float* wsMax = xn + Nn;                 // 64*64*128 floats = 2 MB each
  float* wsM1 = wsMax + NB * NB * 128;
  float* wsM2 = wsM1 + NB * NB * 128;
  float* bsum = wsM2 + NB * NB * 128;     // 256 floats
  float* bcnt = bsum + 256;

  prep_kernel<<<Nn / 4, 256, 0, stream>>>(H, Hb, xn);
  triplet_main<<<NPAIR, 256, 0, stream>>>(Hb, xn, lab, wsMax, wsM1, wsM2);
  merge_kernel<<<256, 256, 0, stream>>>(wsMax, wsM1, wsM2, bsum, bcnt);
  final_kernel<<<1, 256, 0, stream>>>(bsum, bcnt, out);
}

// Round 4
// 202.033 us; speedup vs baseline: 1.0779x; 1.0779x over previous
//
#include <hip/hip_runtime.h>
#include <hip/hip_bf16.h>
#include <stdint.h>

// ---------------- constants ----------------
constexpr int Nn = 8192;
constexpr int Dd = 1024;
constexpr float kAlpha = 0.1f;
constexpr float kEps = 1e-7f;
constexpr float kInf = 3.0e38f;

constexpr int BM = 128, BN = 128, BK = 32;
constexpr int NB = Nn / BM;               // 64 row/col blocks
constexpr int NPAIR = NB * (NB + 1) / 2;  // 2080 upper-triangle tile pairs

using bfx8 = __attribute__((ext_vector_type(8))) __bf16;   // MFMA A/B frag (4 VGPRs)
using f32x4 = __attribute__((ext_vector_type(4))) float;   // MFMA C/D frag

__device__ __forceinline__ unsigned short f2bf(float f) {
  union { float f; unsigned int u; } v; v.f = f;
  unsigned int u = v.u;
  u = u + 0x7fffu + ((u >> 16) & 1u);  // RNE
  return (unsigned short)(u >> 16);
}

__device__ __forceinline__ void min2_insert(float& m1, float& m2, float x) {
  const float lo = fminf(m1, x);
  const float hi = fmaxf(m1, x);
  m1 = lo;
  m2 = fminf(m2, hi);
}

__device__ __forceinline__ void min2_merge(float& m1, float& m2, float o1, float o2) {
  m2 = fminf(fminf(m2, o2), fmaxf(m1, o1));
  m1 = fminf(m1, o1);
}

// ---------------- prep: fp32 -> bf16 + row sq-norms ----------------
__global__ __launch_bounds__(256) void prep_kernel(const float* __restrict__ H,
                                                   unsigned short* __restrict__ Hb,
                                                   float* __restrict__ xn) {
  const int wave = threadIdx.x >> 6;
  const int lane = threadIdx.x & 63;
  const int row = blockIdx.x * 4 + wave;
  const float4* src = (const float4*)(H + (size_t)row * Dd);
  ushort4* dst = (ushort4*)(Hb + (size_t)row * Dd);
  float acc = 0.f;
#pragma unroll
  for (int i = 0; i < 4; ++i) {
    float4 v = src[lane + 64 * i];
    acc = fmaf(v.x, v.x, acc);
    acc = fmaf(v.y, v.y, acc);
    acc = fmaf(v.z, v.z, acc);
    acc = fmaf(v.w, v.w, acc);
    ushort4 o;
    o.x = f2bf(v.x); o.y = f2bf(v.y); o.z = f2bf(v.z); o.w = f2bf(v.w);
    dst[lane + 64 * i] = o;
  }
#pragma unroll
  for (int off = 32; off; off >>= 1) acc += __shfl_xor(acc, off, 64);
  if (lane == 0) xn[row] = acc;
}

// ---------------- main: symmetric fused GEMM + triplet reductions ----------------
// grid = 2080 upper-triangle pairs (I<=J). One 128x128 Gram tile per block,
// reduced BOTH ways (row side -> P[I][J], transposed side -> P[J][I]).
// K-loop: double-buffered LDS, one barrier per iter, prefetch overlaps compute.
// NOTE: no min-waves launch-bounds arg — R3's (256,4) capped VGPR at 64 and
// spilled ~150 MB/dispatch to scratch (WRITE_SIZE 37->192 MB). (256,2) keeps
// the allocator unconstrained in practice; LDS 32 KB still allows 5 blocks/CU.
__global__ __launch_bounds__(256, 2) void triplet_main(
    const unsigned short* __restrict__ Hb, const float* __restrict__ xn,
    const int* __restrict__ lab, float* __restrict__ wsMax,
    float* __restrict__ wsM1, float* __restrict__ wsM2) {
  __shared__ __align__(16) unsigned char smem[32768];  // 2 x (As 8K + Bs 8K)

  const int tid = threadIdx.x;
  const int wave = tid >> 6;
  const int lane = tid & 63;
  const int quad = lane >> 4;
  const int l15 = lane & 15;
  const int wm = wave & 1;
  const int wn = wave >> 1;

  // decode pair index -> (I, J), I <= J
  int b = blockIdx.x, I = 0;
  while (b >= NB - I) { b -= NB - I; ++I; }
  const int J = I + b;
  const bool diag = (I == J);

  const int rowBase = I * BM;
  const int colBase = J * BN;

  // per-lane metadata hoisted above the K-loop
  int lr[16]; float xr[16];
#pragma unroll
  for (int m = 0; m < 4; ++m)
#pragma unroll
    for (int r = 0; r < 4; ++r) {
      const int row = rowBase + wm * 64 + m * 16 + quad * 4 + r;
      lr[m * 4 + r] = lab[row];
      xr[m * 4 + r] = xn[row];
    }
  int lc[4]; float xc[4];
#pragma unroll
  for (int n = 0; n < 4; ++n) {
    const int col = colBase + wn * 64 + n * 16 + l15;
    lc[n] = lab[col];
    xc[n] = xn[col];
  }

  // staging map: wave stages rows [wave*32 + j*16, +16); lane -> (row, 16B seg)
  const int stRow = wave * 32 + (lane >> 2);
  const int stCol = (lane & 3) * 8;  // short offset within a 32-short row
  const unsigned short* gA = Hb + (size_t)(rowBase + stRow) * Dd + stCol;
  const unsigned short* gB = Hb + (size_t)(colBase + stRow) * Dd + stCol;

  auto stage = [&](int buf, int kt) {
    unsigned short* s = (unsigned short*)(smem + (buf << 14));
#pragma unroll
    for (int j = 0; j < 2; ++j) {
      __builtin_amdgcn_global_load_lds(
          (const __attribute__((address_space(1))) void*)(gA + j * 16 * Dd + kt),
          (__attribute__((address_space(3))) void*)&s[(wave * 2 + j) * 512],
          16, 0, 0);
      __builtin_amdgcn_global_load_lds(
          (const __attribute__((address_space(1))) void*)(gB + j * 16 * Dd + kt),
          (__attribute__((address_space(3))) void*)&s[4096 + (wave * 2 + j) * 512],
          16, 0, 0);
    }
  };

  f32x4 acc[4][4];
#pragma unroll
  for (int m = 0; m < 4; ++m)
#pragma unroll
    for (int n = 0; n < 4; ++n) acc[m][n] = {0.f, 0.f, 0.f, 0.f};

  auto compute = [&](int buf) {
    const unsigned short* s = (const unsigned short*)(smem + (buf << 14));
    bfx8 a[4], bb[4];
#pragma unroll
    for (int m = 0; m < 4; ++m)
      a[m] = *(const bfx8*)&s[(wm * 64 + m * 16 + l15) * BK + quad * 8];
#pragma unroll
    for (int n = 0; n < 4; ++n)
      bb[n] = *(const bfx8*)&s[4096 + (wn * 64 + n * 16 + l15) * BK + quad * 8];
#pragma unroll
    for (int m = 0; m < 4; ++m)
#pragma unroll
      for (int n = 0; n < 4; ++n)
        acc[m][n] = __builtin_amdgcn_mfma_f32_16x16x32_bf16(a[m], bb[n], acc[m][n], 0, 0, 0);
  };

  stage(0, 0);
  __syncthreads();  // buf0 ready (cold drain, once)

  constexpr int KIT = Dd / BK;  // 32, even
  for (int k0 = 0; k0 < KIT; k0 += 2) {
    stage(1, (k0 + 1) * BK);           // prefetch odd tile under even compute
    compute(0);
    __syncthreads();                    // odd tile ready; buf0 free
    if (k0 + 2 < KIT) stage(0, (k0 + 2) * BK);  // prefetch next even tile
    compute(1);
    __syncthreads();                    // even tile ready; buf1 free
  }

  // ---- epilogue: dist = xr + xc - 2*G; both-sided masked reductions ----
  float maxp[16], mn1[16], mn2[16];
#pragma unroll
  for (int s = 0; s < 16; ++s) { maxp[s] = 0.f; mn1[s] = kInf; mn2[s] = kInf; }
  float tmaxp[4], tmn1[4], tmn2[4];
#pragma unroll
  for (int n = 0; n < 4; ++n) { tmaxp[n] = 0.f; tmn1[n] = kInf; tmn2[n] = kInf; }

  if (!diag) {
#pragma unroll
    for (int m = 0; m < 4; ++m)
#pragma unroll
      for (int n = 0; n < 4; ++n)
#pragma unroll
        for (int r = 0; r < 4; ++r) {
          const int s = m * 4 + r;
          const float d = fmaf(-2.f, acc[m][n][r], xr[s] + xc[n]);
          const bool eq = (lr[s] == lc[n]);
          const float pos = eq ? d : 0.f;
          const float dn = eq ? kInf : d;
          maxp[s] = fmaxf(maxp[s], pos);
          min2_insert(mn1[s], mn2[s], dn);
          tmaxp[n] = fmaxf(tmaxp[n], pos);
          min2_insert(tmn1[n], tmn2[n], dn);
        }
  } else {
#pragma unroll
    for (int m = 0; m < 4; ++m)
#pragma unroll
      for (int n = 0; n < 4; ++n)
#pragma unroll
        for (int r = 0; r < 4; ++r) {
          const int s = m * 4 + r;
          const bool selfp = (wm == wn) && (m == n) && (quad * 4 + r == l15);
          const float d = fmaf(-2.f, acc[m][n][r], xr[s] + xc[n]);
          const bool eq = (lr[s] == lc[n]);
          const float pos = (eq && !selfp) ? d : 0.f;
          const float dn = eq ? kInf : d;  // self is eq -> excluded from negatives
          maxp[s] = fmaxf(maxp[s], pos);
          min2_insert(mn1[s], mn2[s], dn);
        }
  }

  // cross-lane row merge over the 16 column-lanes
#pragma unroll
  for (int off = 1; off < 16; off <<= 1) {
#pragma unroll
    for (int s = 0; s < 16; ++s) {
      const float om = __shfl_xor(maxp[s], off, 64);
      const float o1 = __shfl_xor(mn1[s], off, 64);
      const float o2 = __shfl_xor(mn2[s], off, 64);
      maxp[s] = fmaxf(maxp[s], om);
      min2_merge(mn1[s], mn2[s], o1, o2);
    }
  }

  // ---- LDS merge phase (K-loop ended with a barrier; LDS free) ----
  float* f = (float*)smem;
  float* rbm = f;            // [128] row-side merged maxpos
  float* rb1 = f + 128;      // [128] min1
  float* rb2 = f + 256;      // [128] min2
  float* tbm = f + 384;      // [2(wm)][2(wn)][4(q)][4(n)][16(l15)] = 1024 each
  float* tb1 = tbm + 1024;
  float* tb2 = tb1 + 1024;

  if (wn == 1 && l15 == 0) {
#pragma unroll
    for (int m = 0; m < 4; ++m)
#pragma unroll
      for (int r = 0; r < 4; ++r) {
        const int s = m * 4 + r;
        const int local = wm * 64 + m * 16 + quad * 4 + r;
        rbm[local] = maxp[s];
        rb1[local] = mn1[s];
        rb2[local] = mn2[s];
      }
  }
#pragma unroll
  for (int n = 0; n < 4; ++n) {
    const int idx = (((wm * 2 + wn) * 4 + quad) * 4 + n) * 16 + l15;
    tbm[idx] = tmaxp[n];
    tb1[idx] = tmn1[n];
    tb2[idx] = tmn2[n];
  }
  __syncthreads();

  // row side: wn==0 waves merge their regs into rb* (element owned by one lane)
  if (wn == 0 && l15 == 0) {
#pragma unroll
    for (int m = 0; m < 4; ++m)
#pragma unroll
      for (int r = 0; r < 4; ++r) {
        const int s = m * 4 + r;
        const int local = wm * 64 + m * 16 + quad * 4 + r;
        rbm[local] = fmaxf(maxp[s], rbm[local]);
        float a1 = mn1[s], a2 = mn2[s];
        min2_merge(a1, a2, rb1[local], rb2[local]);
        rb1[local] = a1;
        rb2[local] = a2;
      }
  }
  // transposed side: wm==0 waves merge tb* over {wm2, quad}; coalesced store
  if (wm == 0 && !diag) {
    const int tn = lane >> 4;
    const int tl = lane & 15;
    float M = 0.f, a1 = kInf, a2 = kInf;
#pragma unroll
    for (int wm2 = 0; wm2 < 2; ++wm2)
#pragma unroll
      for (int q = 0; q < 4; ++q) {
        const int idx = (((wm2 * 2 + wn) * 4 + q) * 4 + tn) * 16 + tl;
        M = fmaxf(M, tbm[idx]);
        min2_merge(a1, a2, tb1[idx], tb2[idx]);
      }
    const size_t p = ((size_t)(J * NB + I)) * 128 + wn * 64 + lane;
    wsMax[p] = M;
    wsM1[p] = a1;
    wsM2[p] = a2;
  }
  __syncthreads();
  // coalesced row-side store from 128 contiguous threads
  if (tid < 128) {
    const size_t p = ((size_t)(I * NB + J)) * 128 + tid;
    wsMax[p] = rbm[tid];
    wsM1[p] = rb1[tid];
    wsM2[p] = rb2[tid];
  }
}

// ---------------- merge: per-row over 64 col-block partials -> block sums ----
// grid = 256 blocks x 256 threads; block handles 32 rows, 8 threads per row.
__global__ __launch_bounds__(256) void merge_kernel(
    const float* __restrict__ wsMax, const float* __restrict__ wsM1,
    const float* __restrict__ wsM2, float* __restrict__ bsum,
    float* __restrict__ bcnt) {
  const int rl = threadIdx.x & 31;  // row within block
  const int p = threadIdx.x >> 5;   // part 0..7 -> bj in [p*8, p*8+8)
  const int row = blockIdx.x * 32 + rl;
  const int bi = row >> 7;
  const int rr = row & 127;
  float mp = 0.f, m1 = kInf, m2 = kInf;
#pragma unroll
  for (int k = 0; k < 8; ++k) {
    const int bj = p * 8 + k;
    const size_t idx = ((size_t)(bi * NB + bj)) * 128 + rr;
    mp = fmaxf(mp, wsMax[idx]);
    min2_merge(m1, m2, wsM1[idx], wsM2[idx]);
  }
  __shared__ float sm[8][32], s1[8][32], s2[8][32];
  sm[p][rl] = mp; s1[p][rl] = m1; s2[p][rl] = m2;
  __syncthreads();
  float ls = 0.f, lc = 0.f;
  if (threadIdx.x < 32) {
    mp = sm[0][rl]; m1 = s1[0][rl]; m2 = s2[0][rl];
#pragma unroll
    for (int q = 1; q < 8; ++q) {
      mp = fmaxf(mp, sm[q][rl]);
      min2_merge(m1, m2, s1[q][rl], s2[q][rl]);
    }
    const float loss = fmaxf(mp - m2 + kAlpha, 0.f);
    ls = (loss > kEps) ? loss : 0.f;
    lc = (loss > kEps) ? 1.f : 0.f;
  }
  if (threadIdx.x < 64) {
#pragma unroll
    for (int off = 32; off; off >>= 1) {
      ls += __shfl_down(ls, off, 64);
      lc += __shfl_down(lc, off, 64);
    }
    if (threadIdx.x == 0) { bsum[blockIdx.x] = ls; bcnt[blockIdx.x] = lc; }
  }
}

// ---------------- final: reduce 256 block sums, divide ----------------
__global__ __launch_bounds__(256) void final_kernel(const float* __restrict__ bsum,
                                                    const float* __restrict__ bcnt,
                                                    float* __restrict__ out) {
  float s = bsum[threadIdx.x];
  float c = bcnt[threadIdx.x];
#pragma unroll
  for (int off = 32; off; off >>= 1) {
    s += __shfl_down(s, off, 64);
    c += __shfl_down(c, off, 64);
  }
  __shared__ float ss[4], sc[4];
  const int w = threadIdx.x >> 6;
  if ((threadIdx.x & 63) == 0) { ss[w] = s; sc[w] = c; }
  __syncthreads();
  if (threadIdx.x == 0)
    out[0] = (ss[0] + ss[1] + ss[2] + ss[3]) / (sc[0] + sc[1] + sc[2] + sc[3]);
}

// ---------------- launch ----------------
extern "C" void kernel_launch(void* const* d_in, const int* in_sizes, int n_in,
                              void* d_out, int out_size, void* d_ws, size_t ws_size,
                              hipStream_t stream) {
  (void)in_sizes; (void)n_in; (void)out_size; (void)ws_size;
  const float* H = (const float*)d_in[0];
  const int* lab = (const int*)d_in[1];
  float* out = (float*)d_out;

  char* ws = (char*)d_ws;
  unsigned short* Hb = (unsigned short*)ws;                              // 16 MB
  float* xn = (float*)(ws + (size_t)Nn * Dd * sizeof(unsigned short));   // 32 KB
  float* wsMax = xn + Nn;                 // 64*64*128 floats = 2 MB each
  float* wsM1 = wsMax + NB * NB * 128;
  float* wsM2 = wsM1 + NB * NB * 128;
  float* bsum = wsM2 + NB * NB * 128;     // 256 floats
  float* bcnt = bsum + 256;

  prep_kernel<<<Nn / 4, 256, 0, stream>>>(H, Hb, xn);
  triplet_main<<<NPAIR, 256, 0, stream>>>(Hb, xn, lab, wsMax, wsM1, wsM2);
  merge_kernel<<<256, 256, 0, stream>>>(wsMax, wsM1, wsM2, bsum, bcnt);
  final_kernel<<<1, 256, 0, stream>>>(bsum, bcnt, out);
}